// Round 1
// baseline (695.824 us; speedup 1.0000x reference)
//
#include <hip/hip_runtime.h>
#include <hip/hip_bf16.h>
#include <stdint.h>

// EntityAttentionLayer: BS=1024, NE=128, IN=512, EMBED=512, NH=8, NA=32, HD=64
// k0: W f32->bf16; k1: fused per-(b,h) qkv+attention -> attn bf16 ws; k2: out proj.

#define NE_ 128
#define NA_ 32
#define NH_ 8
#define HD_ 64
#define IND_ 512
#define EMB_ 512

typedef __attribute__((ext_vector_type(8))) __bf16 bf16x8;
typedef __attribute__((ext_vector_type(4))) float f32x4;

static __device__ __forceinline__ unsigned short bfu(float x) {
  __hip_bfloat16 h = __float2bfloat16(x);
  union { __hip_bfloat16 h1; unsigned short u; } c; c.h1 = h; return c.u;
}
static __device__ __forceinline__ unsigned int pack2(float x, float y) {
  return (unsigned int)bfu(x) | ((unsigned int)bfu(y) << 16);
}
static __device__ __forceinline__ void gload16(const void* g, const void* l) {
  __builtin_amdgcn_global_load_lds(
      (const __attribute__((address_space(1))) unsigned int*)g,
      (__attribute__((address_space(3))) unsigned int*)l, 16, 0, 0);
}

// ---------------- k0: weight conversion ----------------
__global__ __launch_bounds__(256)
void k0_convert(const float* __restrict__ win, const float* __restrict__ wout,
                unsigned short* __restrict__ wb) {
  int t = blockIdx.x * 256 + threadIdx.x;
  int i = t * 4;  // total 1048576 elems: Win 786432 then Wout 262144
  float4 v;
  if (i < 786432) v = *(const float4*)(win + i);
  else            v = *(const float4*)(wout + (i - 786432));
  uint2 pk; pk.x = pack2(v.x, v.y); pk.y = pack2(v.z, v.w);
  *(uint2*)(wb + i) = pk;
}

// ---------------- k1: fused qkv + attention per (b,h) ----------------
// LDS: staging (swizzled linear) unions with S/P/attn-stage. 79.6 KB -> 2 blocks/CU.
struct K1Lds {
  union {
    struct { unsigned short a[128 * 64]; unsigned short b[192 * 64]; } st; // 40960 B
    struct {
      union { float s[32 * 132]; unsigned short attn[32 * 72]; } x;        // 16896 B
      unsigned short p[32 * 136];                                          // 8704 B
    } sm;
  } u;
  unsigned short kk[128 * 72];  // k  [e][d], stride 144 B
  unsigned short vT[64 * 136];  // v^T [d][e], stride 272 B
  unsigned short qq[32 * 72];   // q/8 [a][d], stride 144 B
};

__global__ __launch_bounds__(256, 2)
void k1_fused(const float* __restrict__ ent, const int* __restrict__ pre,
              const unsigned short* __restrict__ wb, unsigned short* __restrict__ attn_out) {
  __shared__ K1Lds sh;
  const int tid = threadIdx.x;
  const int w = tid >> 6, l = tid & 63;
  // XCD-aware mapping: all 8 heads of one batch land on the same XCD (same n&7)
  const int n = blockIdx.x;
  const int xcd = n & 7, kid = n >> 3;
  const int b = xcd * 128 + (kid >> 3);
  const int h = kid & 7;

  const float* E = ent + (size_t)b * (NE_ * IND_);
  char* aB = (char*)sh.u.st.a;
  char* bB = (char*)sh.u.st.b;

  f32x4 acc[2][12];
#pragma unroll
  for (int i = 0; i < 2; ++i)
#pragma unroll
    for (int j = 0; j < 12; ++j) acc[i][j] = (f32x4){0.f, 0.f, 0.f, 0.f};

  const int trow = tid >> 4, tc4 = tid & 15;
  const int hi16 = (l >> 4) << 4;

  // ---- C1 = E(128x512) @ [Wq;Wk;Wv]_h^T (512x192), BK=64, T2 swizzle ----
  for (int kt = 0; kt < 8; ++kt) {
    __syncthreads();
    // stage A: f32 -> bf16, swizzled ds_write
#pragma unroll
    for (int i = 0; i < 8; ++i) {
      int row = trow + i * 16;
      const float4 v = *(const float4*)(E + row * 512 + kt * 64 + tc4 * 4);
      uint2 pk; pk.x = pack2(v.x, v.y); pk.y = pack2(v.z, v.w);
      int x = (row * 128 + tc4 * 8) ^ ((row & 7) << 4);
      *(uint2*)(aB + x) = pk;
    }
    // stage B: global_load_lds (linear dest) with inverse-swizzled source
#pragma unroll
    for (int i = 0; i < 6; ++i) {
      int c = w * 6 + i;
      int x = c * 1024 + l * 16;
      int y = x ^ (((x >> 7) & 7) << 4);
      int idx = y >> 1;
      int r = idx >> 6, col = idx & 63;
      int wrow = ((r >> 6) << 9) + h * 64 + (r & 63);  // q/k/v row groups in W_in
      gload16(wb + (size_t)wrow * 512 + kt * 64 + col, bB + c * 1024);
    }
    __syncthreads();
#pragma unroll
    for (int ks = 0; ks < 2; ++ks) {
      bf16x8 af[2];
#pragma unroll
      for (int i = 0; i < 2; ++i) {
        int row = (w * 2 + i) * 16 + (l & 15);
        int off = (row * 128 + ks * 64 + hi16) ^ ((row & 7) << 4);
        af[i] = *(const bf16x8*)(aB + off);
      }
#pragma unroll
      for (int j = 0; j < 12; ++j) {
        int r = j * 16 + (l & 15);
        int off = (r * 128 + ks * 64 + hi16) ^ ((r & 7) << 4);
        bf16x8 bf = *(const bf16x8*)(bB + off);
        acc[0][j] = __builtin_amdgcn_mfma_f32_16x16x32_bf16(af[0], bf, acc[0][j], 0, 0, 0);
        acc[1][j] = __builtin_amdgcn_mfma_f32_16x16x32_bf16(af[1], bf, acc[1][j], 0, 0, 0);
      }
    }
  }

  // ---- scatter q/8, k, v^T to LDS ----
  {
    const int col16 = l & 15, rg = l >> 4;
#pragma unroll
    for (int i = 0; i < 2; ++i) {
      int mrow = (w * 2 + i) * 16 + rg * 4;
      if (w == 0) {
#pragma unroll
        for (int j = 0; j < 4; ++j) {
          int d = j * 16 + col16;
#pragma unroll
          for (int r = 0; r < 4; ++r) sh.qq[(mrow + r) * 72 + d] = bfu(acc[i][j][r] * 0.125f);
        }
      }
#pragma unroll
      for (int j = 4; j < 8; ++j) {
        int d = (j - 4) * 16 + col16;
#pragma unroll
        for (int r = 0; r < 4; ++r) sh.kk[(mrow + r) * 72 + d] = bfu(acc[i][j][r]);
      }
#pragma unroll
      for (int j = 8; j < 12; ++j) {
        int d = (j - 8) * 16 + col16;
        uint2 pk;
        pk.x = pack2(acc[i][j][0], acc[i][j][1]);
        pk.y = pack2(acc[i][j][2], acc[i][j][3]);
        *(uint2*)((char*)sh.vT + d * 272 + mrow * 2) = pk;
      }
    }
  }
  __syncthreads();

  // ---- S = (q/8) @ k^T : wave w owns e-tiles {2w, 2w+1} ----
  {
    f32x4 sacc[2][2];
#pragma unroll
    for (int i = 0; i < 2; ++i)
#pragma unroll
      for (int j = 0; j < 2; ++j) sacc[i][j] = (f32x4){0.f, 0.f, 0.f, 0.f};
    char* qB = (char*)sh.qq;
    char* kB = (char*)sh.kk;
#pragma unroll
    for (int ks = 0; ks < 2; ++ks) {
      bf16x8 qf[2];
#pragma unroll
      for (int at = 0; at < 2; ++at) {
        int row = at * 16 + (l & 15);
        qf[at] = *(const bf16x8*)(qB + row * 144 + ks * 64 + hi16);
      }
#pragma unroll
      for (int je = 0; je < 2; ++je) {
        int e = (2 * w + je) * 16 + (l & 15);
        bf16x8 kf = *(const bf16x8*)(kB + e * 144 + ks * 64 + hi16);
        sacc[0][je] = __builtin_amdgcn_mfma_f32_16x16x32_bf16(qf[0], kf, sacc[0][je], 0, 0, 0);
        sacc[1][je] = __builtin_amdgcn_mfma_f32_16x16x32_bf16(qf[1], kf, sacc[1][je], 0, 0, 0);
      }
    }
    float* S = sh.u.sm.x.s;
#pragma unroll
    for (int at = 0; at < 2; ++at)
#pragma unroll
      for (int je = 0; je < 2; ++je) {
        int e = (2 * w + je) * 16 + (l & 15);
        int a0 = at * 16 + (l >> 4) * 4;
#pragma unroll
        for (int r = 0; r < 4; ++r) S[(a0 + r) * 132 + e] = sacc[at][je][r];
      }
  }
  __syncthreads();

  // ---- masked softmax over e (8 lanes per agent row) ----
  {
    int a = tid >> 3, ls = tid & 7;
    const int* pm = pre + ((size_t)b * NA_ + a) * NE_ + ls * 16;
    const float* srow = sh.u.sm.x.s + a * 132 + ls * 16;
    float sv[16]; int mk[16];
    float mx = -__builtin_inff();
#pragma unroll
    for (int c = 0; c < 4; ++c) {
      int4 m4 = *(const int4*)(pm + c * 4);
      float4 s4 = *(const float4*)(srow + c * 4);
      mk[c * 4 + 0] = m4.x; sv[c * 4 + 0] = s4.x;
      mk[c * 4 + 1] = m4.y; sv[c * 4 + 1] = s4.y;
      mk[c * 4 + 2] = m4.z; sv[c * 4 + 2] = s4.z;
      mk[c * 4 + 3] = m4.w; sv[c * 4 + 3] = s4.w;
    }
#pragma unroll
    for (int i = 0; i < 16; ++i)
      if (!mk[i]) mx = fmaxf(mx, sv[i]);
    mx = fmaxf(mx, __shfl_xor(mx, 1));
    mx = fmaxf(mx, __shfl_xor(mx, 2));
    mx = fmaxf(mx, __shfl_xor(mx, 4));
    const bool dead = (mx == -__builtin_inff());  // all masked -> softmax NaN -> 0
    float pv[16]; float sum = 0.f;
#pragma unroll
    for (int i = 0; i < 16; ++i) {
      float p = (mk[i] || dead) ? 0.f : __expf(sv[i] - mx);
      pv[i] = p; sum += p;
    }
    sum += __shfl_xor(sum, 1);
    sum += __shfl_xor(sum, 2);
    sum += __shfl_xor(sum, 4);
    float inv = dead ? 0.f : (1.f / sum);
    unsigned short* P = sh.u.sm.p + a * 136 + ls * 16;
#pragma unroll
    for (int c = 0; c < 4; ++c) {
      uint2 pk;
      pk.x = pack2(pv[c * 4 + 0] * inv, pv[c * 4 + 1] * inv);
      pk.y = pack2(pv[c * 4 + 2] * inv, pv[c * 4 + 3] * inv);
      *(uint2*)(P + c * 4) = pk;
    }
  }
  __syncthreads();

  // ---- attn = P @ v : wave w -> (a-tile w>>1, d-tiles (w&1)*2 + {0,1}) ----
  {
    char* pB = (char*)sh.u.sm.p;
    char* vB = (char*)sh.vT;
    int at = w >> 1, dt0 = (w & 1) * 2;
    f32x4 pacc[2] = {(f32x4){0.f, 0.f, 0.f, 0.f}, (f32x4){0.f, 0.f, 0.f, 0.f}};
#pragma unroll
    for (int ks = 0; ks < 4; ++ks) {
      int arow = at * 16 + (l & 15);
      bf16x8 pf = *(const bf16x8*)(pB + arow * 272 + ks * 64 + hi16);
#pragma unroll
      for (int jd = 0; jd < 2; ++jd) {
        int d = (dt0 + jd) * 16 + (l & 15);
        bf16x8 vf = *(const bf16x8*)(vB + d * 272 + ks * 64 + hi16);
        pacc[jd] = __builtin_amdgcn_mfma_f32_16x16x32_bf16(pf, vf, pacc[jd], 0, 0, 0);
      }
    }
    unsigned short* A = sh.u.sm.x.attn;
#pragma unroll
    for (int jd = 0; jd < 2; ++jd) {
      int d = (dt0 + jd) * 16 + (l & 15);
      int a0 = at * 16 + (l >> 4) * 4;
#pragma unroll
      for (int r = 0; r < 4; ++r) A[(a0 + r) * 72 + d] = bfu(pacc[jd][r]);
    }
  }
  __syncthreads();

  // ---- coalesced write of attn tile (32x64 bf16) ----
  {
    int row = tid >> 3, c8 = (tid & 7) * 8;
    uint4 v = *(const uint4*)((const char*)sh.u.sm.x.attn + row * 144 + c8 * 2);
    *(uint4*)(attn_out + ((size_t)(b * NA_ + row) * EMB_ + h * HD_ + c8)) = v;
  }
}

// ---------------- k2: out = attn @ W_out^T + b_out, post-mask ----------------
__global__ __launch_bounds__(256, 2)
void k2_out(const unsigned short* __restrict__ attn, const unsigned short* __restrict__ wob,
            const float* __restrict__ bout, const int* __restrict__ post,
            float* __restrict__ out) {
  __shared__ struct { unsigned short a[128 * 64]; unsigned short b[128 * 64]; } sh;
  const int tid = threadIdx.x, w = tid >> 6, l = tid & 63;
  const int n = blockIdx.x;
  const int sw = (n & 7) * 128 + (n >> 3);  // XCD swizzle (1024 % 8 == 0)
  const int mt = sw >> 2, ntb = sw & 3;
  char* aB = (char*)sh.a;
  char* bB = (char*)sh.b;
  const int hi16 = (l >> 4) << 4;

  f32x4 acc[2][8];
#pragma unroll
  for (int i = 0; i < 2; ++i)
#pragma unroll
    for (int j = 0; j < 8; ++j) acc[i][j] = (f32x4){0.f, 0.f, 0.f, 0.f};

  for (int kt = 0; kt < 8; ++kt) {
    __syncthreads();
#pragma unroll
    for (int i = 0; i < 4; ++i) {
      int c = w * 4 + i;
      int x = c * 1024 + l * 16;
      int y = x ^ (((x >> 7) & 7) << 4);
      int idx = y >> 1, r = idx >> 6, col = idx & 63;
      gload16(attn + (size_t)(mt * 128 + r) * 512 + kt * 64 + col, aB + c * 1024);
      gload16(wob + (size_t)(ntb * 128 + r) * 512 + kt * 64 + col, bB + c * 1024);
    }
    __syncthreads();
#pragma unroll
    for (int ks = 0; ks < 2; ++ks) {
      bf16x8 af[2];
#pragma unroll
      for (int i = 0; i < 2; ++i) {
        int row = (w * 2 + i) * 16 + (l & 15);
        af[i] = *(const bf16x8*)(aB + ((row * 128 + ks * 64 + hi16) ^ ((row & 7) << 4)));
      }
#pragma unroll
      for (int j = 0; j < 8; ++j) {
        int r = j * 16 + (l & 15);
        bf16x8 bf = *(const bf16x8*)(bB + ((r * 128 + ks * 64 + hi16) ^ ((r & 7) << 4)));
        acc[0][j] = __builtin_amdgcn_mfma_f32_16x16x32_bf16(af[0], bf, acc[0][j], 0, 0, 0);
        acc[1][j] = __builtin_amdgcn_mfma_f32_16x16x32_bf16(af[1], bf, acc[1][j], 0, 0, 0);
      }
    }
  }

  int pmv[2][4];
#pragma unroll
  for (int i = 0; i < 2; ++i) {
    int m0 = mt * 128 + w * 32 + i * 16 + (l >> 4) * 4;
#pragma unroll
    for (int r = 0; r < 4; ++r) pmv[i][r] = post[m0 + r];
  }
#pragma unroll
  for (int j = 0; j < 8; ++j) {
    int nn = ntb * 128 + j * 16 + (l & 15);
    float bo = bout[nn];
#pragma unroll
    for (int i = 0; i < 2; ++i) {
      int m0 = mt * 128 + w * 32 + i * 16 + (l >> 4) * 4;
#pragma unroll
      for (int r = 0; r < 4; ++r) {
        float v = pmv[i][r] ? 0.f : (acc[i][j][r] + bo);
        out[(size_t)(m0 + r) * 512 + nn] = v;
      }
    }
  }
}

extern "C" void kernel_launch(void* const* d_in, const int* in_sizes, int n_in,
                              void* d_out, int out_size, void* d_ws, size_t ws_size,
                              hipStream_t stream) {
  const float* ent  = (const float*)d_in[0];
  const int*   pre  = (const int*)d_in[1];
  const int*   post = (const int*)d_in[2];
  const float* win  = (const float*)d_in[3];
  const float* wout = (const float*)d_in[4];
  const float* bout = (const float*)d_in[5];
  float* out = (float*)d_out;

  unsigned short* wsb   = (unsigned short*)d_ws;
  unsigned short* winb  = wsb;            // 786432 bf16
  unsigned short* woutb = wsb + 786432;   // 262144 bf16
  unsigned short* attnb = wsb + 1048576;  // 1024*32*512 bf16 (~33.5 MB)

  hipLaunchKernelGGL(k0_convert, dim3(1024), dim3(256), 0, stream, win, wout, wsb);
  hipLaunchKernelGGL(k1_fused, dim3(8192), dim3(256), 0, stream, ent, pre, winb, attnb);
  hipLaunchKernelGGL(k2_out, dim3(1024), dim3(256), 0, stream, attnb, woutb, bout, post, out);
}